// Round 6
// baseline (948.015 us; speedup 1.0000x reference)
//
#include <hip/hip_runtime.h>

#define DIM 128
typedef unsigned int uint;
typedef unsigned short ushort;

// bf16 pack (RNE)
__device__ __forceinline__ ushort f2bf(float x) {
    uint u = __float_as_uint(x);
    u = u + 0x7FFFu + ((u >> 16) & 1u);
    return (ushort)(u >> 16);
}
__device__ __forceinline__ uint pack2(float a, float b) {
    return (uint)f2bf(a) | ((uint)f2bf(b) << 16);
}

__device__ __forceinline__ int src_bucket(int s, int Q) {
    int p = s / Q;
    return p > 3 ? 3 : p;
}

// ---------------- degree count into 4 src-range buckets per dst ----------------
__global__ __launch_bounds__(256) void k_count4(const int* __restrict__ src,
                                                const int* __restrict__ dst,
                                                int* __restrict__ deg4, int E, int Q) {
    int t = blockIdx.x * 256 + threadIdx.x;
    if (t < E) {
        int p = src_bucket(src[t], Q);
        atomicAdd(&deg4[(dst[t] << 2) + p], 1);
    }
}

// ---------------- single-block exclusive scan over 4N bucket counts ----------------
__global__ __launch_bounds__(1024) void k_scan4(const int* __restrict__ deg4,
                                                int* __restrict__ rowptr4,
                                                int* __restrict__ cursor4, int M) {
    int t = threadIdx.x;
    int chunk = (M + 1023) >> 10;
    int s0 = t * chunk, s1 = min(s0 + chunk, M);
    int sum = 0;
    for (int i = s0; i < s1; ++i) sum += deg4[i];
    __shared__ int ps[1024];
    ps[t] = sum;
    __syncthreads();
    for (int off = 1; off < 1024; off <<= 1) {
        int v = (t >= off) ? ps[t - off] : 0;
        __syncthreads();
        ps[t] += v;
        __syncthreads();
    }
    int base = (t == 0) ? 0 : ps[t - 1];
    for (int i = s0; i < s1; ++i) { rowptr4[i] = base; cursor4[i] = base; base += deg4[i]; }
    if (t == 0) rowptr4[M] = ps[1023];
}

__global__ __launch_bounds__(256) void k_dinv(const int* __restrict__ rowptr4,
                                              float* __restrict__ dinv, int N) {
    int t = blockIdx.x * 256 + threadIdx.x;
    if (t < N) {
        int deg = rowptr4[(t << 2) + 4] - rowptr4[t << 2];
        dinv[t] = rsqrtf((float)(deg + 1));  // +1 = self-loop
    }
}

// ---------------- CSR fill: {src, weight}, grouped by (dst, src-bucket) ----------------
__global__ __launch_bounds__(256) void k_fill4(const int* __restrict__ src,
                                               const int* __restrict__ dst,
                                               const float* __restrict__ dinv,
                                               int* __restrict__ cursor4,
                                               int2* __restrict__ csr, int E, int Q) {
    int e = blockIdx.x * 256 + threadIdx.x;
    if (e >= E) return;
    int s = src[e], d = dst[e];
    int p = src_bucket(s, Q);
    int pos = atomicAdd(&cursor4[(d << 2) + p], 1);
    float w = dinv[s] * dinv[d];
    csr[pos] = make_int2(s, __float_as_int(w));
}

// ---------------- dense GEMM: H(bf16) = (cvec +) f(X) @ W ----------------
template<bool RELU_IN, bool ADD_C>
__global__ __launch_bounds__(256) void k_gemm(const float* __restrict__ X,
                                              const float* __restrict__ W,
                                              const float* __restrict__ Cvec,
                                              ushort* __restrict__ H, int n) {
    __shared__ float sW[64 * DIM];   // 32 KB, one K-chunk of W [k2][j]
    __shared__ float sX[32][DIM];    // 16 KB
    const int jq = threadIdx.x & 31;
    const int rr = threadIdx.x >> 5;   // 0..7
    float4 cj = ADD_C ? ((const float4*)Cvec)[jq] : make_float4(0.f, 0.f, 0.f, 0.f);
    for (int base = blockIdx.x * 32; base < n; base += gridDim.x * 32) {
        __syncthreads();
        for (int u = threadIdx.x; u < 32 * 32; u += 256) {
            int row = u >> 5, c4 = u & 31;
            int gi = base + row;
            float4 v = make_float4(0.f, 0.f, 0.f, 0.f);
            if (gi < n) v = ((const float4*)(X + (size_t)gi * DIM))[c4];
            if (RELU_IN) {
                v.x = fmaxf(v.x, 0.f); v.y = fmaxf(v.y, 0.f);
                v.z = fmaxf(v.z, 0.f); v.w = fmaxf(v.w, 0.f);
            }
            ((float4*)sX[row])[c4] = v;
        }
        float4 a0 = cj, a1 = cj, a2 = cj, a3 = cj;
        for (int kk = 0; kk < DIM; kk += 64) {
            __syncthreads();
            for (int u = threadIdx.x; u < 64 * 32; u += 256)
                ((float4*)sW)[u] = ((const float4*)(W + (size_t)kk * DIM))[u];
            __syncthreads();
            #pragma unroll 8
            for (int k2 = 0; k2 < 64; ++k2) {
                int k = kk + k2;
                float4 w4 = ((const float4*)sW)[k2 * 32 + jq];
                float x0 = sX[rr * 4 + 0][k], x1 = sX[rr * 4 + 1][k];
                float x2 = sX[rr * 4 + 2][k], x3 = sX[rr * 4 + 3][k];
                a0.x = fmaf(x0, w4.x, a0.x); a0.y = fmaf(x0, w4.y, a0.y);
                a0.z = fmaf(x0, w4.z, a0.z); a0.w = fmaf(x0, w4.w, a0.w);
                a1.x = fmaf(x1, w4.x, a1.x); a1.y = fmaf(x1, w4.y, a1.y);
                a1.z = fmaf(x1, w4.z, a1.z); a1.w = fmaf(x1, w4.w, a1.w);
                a2.x = fmaf(x2, w4.x, a2.x); a2.y = fmaf(x2, w4.y, a2.y);
                a2.z = fmaf(x2, w4.z, a2.z); a2.w = fmaf(x2, w4.w, a2.w);
                a3.x = fmaf(x3, w4.x, a3.x); a3.y = fmaf(x3, w4.y, a3.y);
                a3.z = fmaf(x3, w4.z, a3.z); a3.w = fmaf(x3, w4.w, a3.w);
            }
        }
        int i0 = base + rr * 4;
        if (i0 + 0 < n) ((uint2*)(H + (size_t)(i0 + 0) * DIM))[jq] =
            make_uint2(pack2(a0.x, a0.y), pack2(a0.z, a0.w));
        if (i0 + 1 < n) ((uint2*)(H + (size_t)(i0 + 1) * DIM))[jq] =
            make_uint2(pack2(a1.x, a1.y), pack2(a1.z, a1.w));
        if (i0 + 2 < n) ((uint2*)(H + (size_t)(i0 + 2) * DIM))[jq] =
            make_uint2(pack2(a2.x, a2.y), pack2(a2.z, a2.w));
        if (i0 + 3 < n) ((uint2*)(H + (size_t)(i0 + 3) * DIM))[jq] =
            make_uint2(pack2(a3.x, a3.y), pack2(a3.z, a3.w));
    }
}

// ---------------- c[j] = sum_k relu(posts[root][k]) * W2[k][j] ----------------
__global__ __launch_bounds__(DIM) void k_cvec(const float* __restrict__ posts,
                                              const int* __restrict__ root,
                                              const float* __restrict__ W2,
                                              float* __restrict__ cvec) {
    int j = threadIdx.x;
    const float* xr = posts + (size_t)root[0] * DIM;
    float acc = 0.0f;
    #pragma unroll 8
    for (int k = 0; k < DIM; ++k)
        acc = fmaf(fmaxf(xr[k], 0.0f), W2[k * DIM + j], acc);
    cvec[j] = acc;
}

// unpack uint2 (4 bf16) and fma into acc
__device__ __forceinline__ void bf4_fma(uint2 p, float w,
                                        float& ax, float& ay, float& az, float& aw) {
    ax = fmaf(__uint_as_float(p.x << 16), w, ax);
    ay = fmaf(__uint_as_float(p.x & 0xFFFF0000u), w, ay);
    az = fmaf(__uint_as_float(p.y << 16), w, az);
    aw = fmaf(__uint_as_float(p.y & 0xFFFF0000u), w, aw);
}

// 8-edge-deep accumulate of bf16 h rows into (ax..aw) for lane-quad q.
__device__ __forceinline__ void edge_accum(const int2* __restrict__ csr,
                                           int beg, int end, int q,
                                           const ushort* __restrict__ h,
                                           float& ax, float& ay, float& az, float& aw) {
    int e = beg;
    for (; e + 8 <= end; e += 8) {
        int2 ee[8];
        uint2 vv[8];
        #pragma unroll
        for (int u = 0; u < 8; ++u) ee[u] = csr[e + u];
        #pragma unroll
        for (int u = 0; u < 8; ++u)
            vv[u] = ((const uint2*)(h + (size_t)ee[u].x * DIM))[q];
        #pragma unroll
        for (int u = 0; u < 8; ++u)
            bf4_fma(vv[u], __int_as_float(ee[u].y), ax, ay, az, aw);
    }
    int rem = end - e;
    if (rem > 0) {
        int2 ee[8];
        uint2 vv[8];
        #pragma unroll
        for (int u = 0; u < 8; ++u)
            ee[u] = (u < rem) ? csr[e + u] : make_int2(0, 0);
        #pragma unroll
        for (int u = 0; u < 8; ++u)
            vv[u] = (u < rem) ? ((const uint2*)(h + (size_t)ee[u].x * DIM))[q]
                              : make_uint2(0u, 0u);
        #pragma unroll
        for (int u = 0; u < 8; ++u)
            bf4_fma(vv[u], __int_as_float(ee[u].y), ax, ay, az, aw);
    }
}

// ---------------- gather layer 1, one src-bucket pass ----------------
// FIRST: conv1 = partial. MID: conv1 += partial. LAST: conv1 += partial+self+b1, root out.
template<bool FIRST, bool LAST>
__global__ __launch_bounds__(256) void k_gather1(const int2* __restrict__ csr,
                                                 const int* __restrict__ rowptr4,
                                                 const float* __restrict__ dinv,
                                                 const ushort* __restrict__ h,
                                                 const float* __restrict__ b1,
                                                 const int* __restrict__ root,
                                                 float* __restrict__ conv1,
                                                 float* __restrict__ out, int N, int pass) {
    int q = threadIdx.x & 31;
    int g = threadIdx.x >> 5;   // 0..7
    float4 bv = ((const float4*)b1)[q];
    int rt = root[0];
    for (int d = blockIdx.x * 8 + g; d < N; d += gridDim.x * 8) {
        int idx = (d << 2) + pass;
        int beg = rowptr4[idx], end = rowptr4[idx + 1];
        float ax = 0.f, ay = 0.f, az = 0.f, aw = 0.f;
        edge_accum(csr, beg, end, q, h, ax, ay, az, aw);
        float4* crow = (float4*)(conv1 + (size_t)d * DIM) + q;
        float4 r = make_float4(ax, ay, az, aw);
        if (!FIRST) {
            float4 c = *crow;
            r.x += c.x; r.y += c.y; r.z += c.z; r.w += c.w;
        }
        if (LAST) {
            float di = dinv[d], sl = di * di;
            uint2 hv = ((const uint2*)(h + (size_t)d * DIM))[q];
            r.x = fmaf(__uint_as_float(hv.x << 16), sl, r.x) + bv.x;
            r.y = fmaf(__uint_as_float(hv.x & 0xFFFF0000u), sl, r.y) + bv.y;
            r.z = fmaf(__uint_as_float(hv.y << 16), sl, r.z) + bv.z;
            r.w = fmaf(__uint_as_float(hv.y & 0xFFFF0000u), sl, r.w) + bv.w;
        }
        *crow = r;
        if (LAST && d == rt) ((float4*)out)[q] = r;   // conv1_root (no relu)
    }
}

// ---------------- gather layer 2, one src-bucket pass (acc2 = reused conv1 buffer) ----
// LAST: v = acc2 + partial + self + b2 -> relu -> fused column mean.
template<bool FIRST, bool LAST>
__global__ __launch_bounds__(256) void k_gather2(const int2* __restrict__ csr,
                                                 const int* __restrict__ rowptr4,
                                                 const float* __restrict__ dinv,
                                                 const ushort* __restrict__ h,
                                                 const float* __restrict__ b2,
                                                 float* __restrict__ acc2,
                                                 float* __restrict__ meanacc, int N, int pass) {
    int q = threadIdx.x & 31;
    int g = threadIdx.x >> 5;   // 0..7
    float4 bv = ((const float4*)b2)[q];
    float sx = 0.f, sy = 0.f, sz = 0.f, sw = 0.f;
    for (int d = blockIdx.x * 8 + g; d < N; d += gridDim.x * 8) {
        int idx = (d << 2) + pass;
        int beg = rowptr4[idx], end = rowptr4[idx + 1];
        float ax = 0.f, ay = 0.f, az = 0.f, aw = 0.f;
        edge_accum(csr, beg, end, q, h, ax, ay, az, aw);
        float4* crow = (float4*)(acc2 + (size_t)d * DIM) + q;
        float4 r = make_float4(ax, ay, az, aw);
        if (!FIRST) {
            float4 c = *crow;
            r.x += c.x; r.y += c.y; r.z += c.z; r.w += c.w;
        }
        if (!LAST) {
            *crow = r;
        } else {
            float di = dinv[d], sl = di * di;
            uint2 hv = ((const uint2*)(h + (size_t)d * DIM))[q];
            sx += fmaxf(fmaf(__uint_as_float(hv.x << 16), sl, r.x) + bv.x, 0.f);
            sy += fmaxf(fmaf(__uint_as_float(hv.x & 0xFFFF0000u), sl, r.y) + bv.y, 0.f);
            sz += fmaxf(fmaf(__uint_as_float(hv.y << 16), sl, r.z) + bv.z, 0.f);
            sw += fmaxf(fmaf(__uint_as_float(hv.y & 0xFFFF0000u), sl, r.w) + bv.w, 0.f);
        }
    }
    if (LAST) {
        __shared__ float4 sp[256];
        sp[threadIdx.x] = make_float4(sx, sy, sz, sw);
        __syncthreads();
        if (threadIdx.x < 32) {
            float4 s = sp[threadIdx.x];
            #pragma unroll
            for (int gg = 1; gg < 8; ++gg) {
                float4 o = sp[gg * 32 + threadIdx.x];
                s.x += o.x; s.y += o.y; s.z += o.z; s.w += o.w;
            }
            unsafeAtomicAdd(&meanacc[q * 4 + 0], s.x);
            unsafeAtomicAdd(&meanacc[q * 4 + 1], s.y);
            unsafeAtomicAdd(&meanacc[q * 4 + 2], s.z);
            unsafeAtomicAdd(&meanacc[q * 4 + 3], s.w);
        }
    }
}

__global__ __launch_bounds__(DIM) void k_reduce(const float* __restrict__ meanacc,
                                                float* __restrict__ out, int N) {
    int j = threadIdx.x;
    out[DIM + j] = meanacc[j] / (float)N;
}

extern "C" void kernel_launch(void* const* d_in, const int* in_sizes, int n_in,
                              void* d_out, int out_size, void* d_ws, size_t ws_size,
                              hipStream_t stream) {
    const float* posts = (const float*)d_in[0];
    const int*   eidx  = (const int*)d_in[1];
    const int*   root  = (const int*)d_in[2];
    const float* W1    = (const float*)d_in[3];
    const float* b1    = (const float*)d_in[4];
    const float* W2    = (const float*)d_in[5];
    const float* b2    = (const float*)d_in[6];
    float* out = (float*)d_out;

    int N = in_sizes[0] / DIM;
    int E = in_sizes[1] / 2;
    int Q = (N + 3) / 4;     // src-range quartile width (~3.2 MB bf16 h-slice)
    const int* src = eidx;
    const int* dst = eidx + E;

    char* ws = (char*)d_ws;
    size_t off = 0;
    auto alloc = [&](size_t bytes) {
        void* p = ws + off;
        off += (bytes + 511) & ~(size_t)511;
        return p;
    };
    int*    deg4    = (int*)   alloc((size_t)N * 16);        // 4N bucket counts
    int*    rowptr4 = (int*)   alloc(((size_t)N * 4 + 1) * 4);
    int*    cursor4 = (int*)   alloc((size_t)N * 16);
    float*  dinv    = (float*) alloc((size_t)N * 4);
    float*  cvec    = (float*) alloc(DIM * 4);
    float*  meanacc = (float*) alloc(DIM * 4);
    int2*   csr     = (int2*)  alloc((size_t)E * 8);
    ushort* h       = (ushort*)alloc((size_t)N * DIM * 2);   // bf16 h1, then h2
    float*  conv1   = (float*) alloc((size_t)N * DIM * 4);   // conv1 accum / conv2 accum

    hipMemsetAsync(deg4, 0, (size_t)N * 16, stream);
    hipMemsetAsync(meanacc, 0, DIM * 4, stream);

    // CSR build: 4 src-range buckets per dst (once, shared by both layers)
    k_count4<<<(E + 255) / 256, 256, 0, stream>>>(src, dst, deg4, E, Q);
    k_scan4<<<1, 1024, 0, stream>>>(deg4, rowptr4, cursor4, N * 4);
    k_dinv<<<(N + 255) / 256, 256, 0, stream>>>(rowptr4, dinv, N);
    k_fill4<<<(E + 255) / 256, 256, 0, stream>>>(src, dst, dinv, cursor4, csr, E, Q);

    // layer 1
    k_gemm<false, false><<<512, 256, 0, stream>>>(posts, W1, nullptr, h, N);
    k_gather1<true,  false><<<2048, 256, 0, stream>>>(csr, rowptr4, dinv, h, b1, root, conv1, out, N, 0);
    k_gather1<false, false><<<2048, 256, 0, stream>>>(csr, rowptr4, dinv, h, b1, root, conv1, out, N, 1);
    k_gather1<false, false><<<2048, 256, 0, stream>>>(csr, rowptr4, dinv, h, b1, root, conv1, out, N, 2);
    k_gather1<false, true ><<<2048, 256, 0, stream>>>(csr, rowptr4, dinv, h, b1, root, conv1, out, N, 3);

    // layer 2: h2 = cvec + relu(conv1) @ W2[128:], cvec = relu(post_root) @ W2[:128]
    k_cvec<<<1, DIM, 0, stream>>>(posts, root, W2, cvec);
    k_gemm<true, true><<<512, 256, 0, stream>>>(conv1, W2 + DIM * DIM, cvec, h, N);
    // conv1 buffer is now free -> reuse as conv2 accumulator
    k_gather2<true,  false><<<2048, 256, 0, stream>>>(csr, rowptr4, dinv, h, b2, conv1, meanacc, N, 0);
    k_gather2<false, false><<<2048, 256, 0, stream>>>(csr, rowptr4, dinv, h, b2, conv1, meanacc, N, 1);
    k_gather2<false, false><<<2048, 256, 0, stream>>>(csr, rowptr4, dinv, h, b2, conv1, meanacc, N, 2);
    k_gather2<false, true ><<<2048, 256, 0, stream>>>(csr, rowptr4, dinv, h, b2, conv1, meanacc, N, 3);
    k_reduce<<<1, DIM, 0, stream>>>(meanacc, out, N);
}

// Round 8
// 440.174 us; speedup vs baseline: 2.1537x; 2.1537x over previous
//
#include <hip/hip_runtime.h>

#define DIM 128
typedef unsigned int uint;
typedef unsigned short ushort;

// bf16 pack (RNE)
__device__ __forceinline__ ushort f2bf(float x) {
    uint u = __float_as_uint(x);
    u = u + 0x7FFFu + ((u >> 16) & 1u);
    return (ushort)(u >> 16);
}
__device__ __forceinline__ uint pack2(float a, float b) {
    return (uint)f2bf(a) | ((uint)f2bf(b) << 16);
}

// ---------------- degree count ----------------
__global__ __launch_bounds__(256) void k_count(const int* __restrict__ dst,
                                               int* __restrict__ deg, int E) {
    int t = blockIdx.x * 256 + threadIdx.x;
    if (t < E) atomicAdd(&deg[dst[t]], 1);
}

__global__ __launch_bounds__(256) void k_dinv(const int* __restrict__ deg,
                                              float* __restrict__ dinv, int N) {
    int t = blockIdx.x * 256 + threadIdx.x;
    if (t < N) dinv[t] = rsqrtf((float)(deg[t] + 1));  // +1 = self-loop
}

// ---------------- parallel exclusive scan: blockwise -> seg -> add ----------------
__global__ __launch_bounds__(256) void k_scanA(const int* __restrict__ deg,
                                               int* __restrict__ rowptr,
                                               int* __restrict__ segsum, int N) {
    int i = blockIdx.x * 256 + threadIdx.x;
    int v = (i < N) ? deg[i] : 0;
    __shared__ int ps[256];
    ps[threadIdx.x] = v;
    __syncthreads();
    for (int off = 1; off < 256; off <<= 1) {
        int u = (threadIdx.x >= off) ? ps[threadIdx.x - off] : 0;
        __syncthreads();
        ps[threadIdx.x] += u;
        __syncthreads();
    }
    if (i < N) rowptr[i] = ps[threadIdx.x] - v;   // exclusive within block
    if (threadIdx.x == 255) segsum[blockIdx.x] = ps[255];
}

__global__ __launch_bounds__(256) void k_scanB(int* __restrict__ segsum, int nseg) {
    int t = threadIdx.x;
    int v = (t < nseg) ? segsum[t] : 0;
    __shared__ int ps[256];
    ps[t] = v;
    __syncthreads();
    for (int off = 1; off < 256; off <<= 1) {
        int u = (t >= off) ? ps[t - off] : 0;
        __syncthreads();
        ps[t] += u;
        __syncthreads();
    }
    if (t < nseg) segsum[t] = ps[t] - v;
}

__global__ __launch_bounds__(256) void k_scanC(int* __restrict__ rowptr,
                                               const int* __restrict__ segsum,
                                               int* __restrict__ cursor, int N, int E) {
    int i = blockIdx.x * 256 + threadIdx.x;
    if (i < N) {
        int r = rowptr[i] + segsum[blockIdx.x];
        rowptr[i] = r;
        cursor[i] = r;
    }
    if (i == 0) rowptr[N] = E;
}

// ---------------- CSR fill: {src, weight} per edge, grouped by dst ----------------
__global__ __launch_bounds__(256) void k_fill(const int* __restrict__ src,
                                              const int* __restrict__ dst,
                                              const float* __restrict__ dinv,
                                              int* __restrict__ cursor,
                                              int2* __restrict__ csr, int E) {
    int e = blockIdx.x * 256 + threadIdx.x;
    if (e >= E) return;
    int s = src[e], d = dst[e];
    int p = atomicAdd(&cursor[d], 1);
    float w = dinv[s] * dinv[d];
    csr[p] = make_int2(s, __float_as_int(w));
}

// ---------------- dense GEMM: H(bf16) = (cvec +) f(X) @ W ----------------
template<bool RELU_IN, bool ADD_C>
__global__ __launch_bounds__(256) void k_gemm(const float* __restrict__ X,
                                              const float* __restrict__ W,
                                              const float* __restrict__ Cvec,
                                              ushort* __restrict__ H, int n) {
    __shared__ float sW[64 * DIM];   // 32 KB, one K-chunk of W [k2][j]
    __shared__ float sX[32][DIM];    // 16 KB
    const int jq = threadIdx.x & 31;
    const int rr = threadIdx.x >> 5;   // 0..7
    float4 cj = ADD_C ? ((const float4*)Cvec)[jq] : make_float4(0.f, 0.f, 0.f, 0.f);
    for (int base = blockIdx.x * 32; base < n; base += gridDim.x * 32) {
        __syncthreads();
        for (int u = threadIdx.x; u < 32 * 32; u += 256) {
            int row = u >> 5, c4 = u & 31;
            int gi = base + row;
            float4 v = make_float4(0.f, 0.f, 0.f, 0.f);
            if (gi < n) v = ((const float4*)(X + (size_t)gi * DIM))[c4];
            if (RELU_IN) {
                v.x = fmaxf(v.x, 0.f); v.y = fmaxf(v.y, 0.f);
                v.z = fmaxf(v.z, 0.f); v.w = fmaxf(v.w, 0.f);
            }
            ((float4*)sX[row])[c4] = v;
        }
        float4 a0 = cj, a1 = cj, a2 = cj, a3 = cj;
        for (int kk = 0; kk < DIM; kk += 64) {
            __syncthreads();
            for (int u = threadIdx.x; u < 64 * 32; u += 256)
                ((float4*)sW)[u] = ((const float4*)(W + (size_t)kk * DIM))[u];
            __syncthreads();
            #pragma unroll 8
            for (int k2 = 0; k2 < 64; ++k2) {
                int k = kk + k2;
                float4 w4 = ((const float4*)sW)[k2 * 32 + jq];
                float x0 = sX[rr * 4 + 0][k], x1 = sX[rr * 4 + 1][k];
                float x2 = sX[rr * 4 + 2][k], x3 = sX[rr * 4 + 3][k];
                a0.x = fmaf(x0, w4.x, a0.x); a0.y = fmaf(x0, w4.y, a0.y);
                a0.z = fmaf(x0, w4.z, a0.z); a0.w = fmaf(x0, w4.w, a0.w);
                a1.x = fmaf(x1, w4.x, a1.x); a1.y = fmaf(x1, w4.y, a1.y);
                a1.z = fmaf(x1, w4.z, a1.z); a1.w = fmaf(x1, w4.w, a1.w);
                a2.x = fmaf(x2, w4.x, a2.x); a2.y = fmaf(x2, w4.y, a2.y);
                a2.z = fmaf(x2, w4.z, a2.z); a2.w = fmaf(x2, w4.w, a2.w);
                a3.x = fmaf(x3, w4.x, a3.x); a3.y = fmaf(x3, w4.y, a3.y);
                a3.z = fmaf(x3, w4.z, a3.z); a3.w = fmaf(x3, w4.w, a3.w);
            }
        }
        int i0 = base + rr * 4;
        if (i0 + 0 < n) ((uint2*)(H + (size_t)(i0 + 0) * DIM))[jq] =
            make_uint2(pack2(a0.x, a0.y), pack2(a0.z, a0.w));
        if (i0 + 1 < n) ((uint2*)(H + (size_t)(i0 + 1) * DIM))[jq] =
            make_uint2(pack2(a1.x, a1.y), pack2(a1.z, a1.w));
        if (i0 + 2 < n) ((uint2*)(H + (size_t)(i0 + 2) * DIM))[jq] =
            make_uint2(pack2(a2.x, a2.y), pack2(a2.z, a2.w));
        if (i0 + 3 < n) ((uint2*)(H + (size_t)(i0 + 3) * DIM))[jq] =
            make_uint2(pack2(a3.x, a3.y), pack2(a3.z, a3.w));
    }
}

// ---------------- c[j] = sum_k relu(posts[root][k]) * W2[k][j] ----------------
__global__ __launch_bounds__(DIM) void k_cvec(const float* __restrict__ posts,
                                              const int* __restrict__ root,
                                              const float* __restrict__ W2,
                                              float* __restrict__ cvec) {
    int j = threadIdx.x;
    const float* xr = posts + (size_t)root[0] * DIM;
    float acc = 0.0f;
    #pragma unroll 8
    for (int k = 0; k < DIM; ++k)
        acc = fmaf(fmaxf(xr[k], 0.0f), W2[k * DIM + j], acc);
    cvec[j] = acc;
}

// unpack uint2 (4 bf16) and fma into acc
__device__ __forceinline__ void bf4_fma(uint2 p, float w,
                                        float& ax, float& ay, float& az, float& aw) {
    ax = fmaf(__uint_as_float(p.x << 16), w, ax);
    ay = fmaf(__uint_as_float(p.x & 0xFFFF0000u), w, ay);
    az = fmaf(__uint_as_float(p.y << 16), w, az);
    aw = fmaf(__uint_as_float(p.y & 0xFFFF0000u), w, aw);
}

// 8-edge-deep accumulate of bf16 h rows into (ax..aw) for lane-quad q.
__device__ __forceinline__ void edge_accum(const int2* __restrict__ csr,
                                           int beg, int end, int q,
                                           const ushort* __restrict__ h,
                                           float& ax, float& ay, float& az, float& aw) {
    int e = beg;
    for (; e + 8 <= end; e += 8) {
        int2 ee[8];
        uint2 vv[8];
        #pragma unroll
        for (int u = 0; u < 8; ++u) ee[u] = csr[e + u];
        #pragma unroll
        for (int u = 0; u < 8; ++u)
            vv[u] = ((const uint2*)(h + (size_t)ee[u].x * DIM))[q];
        #pragma unroll
        for (int u = 0; u < 8; ++u)
            bf4_fma(vv[u], __int_as_float(ee[u].y), ax, ay, az, aw);
    }
    int rem = end - e;
    if (rem > 0) {
        int2 ee[8];
        uint2 vv[8];
        #pragma unroll
        for (int u = 0; u < 8; ++u)
            ee[u] = (u < rem) ? csr[e + u] : make_int2(0, 0);
        #pragma unroll
        for (int u = 0; u < 8; ++u)
            vv[u] = (u < rem) ? ((const uint2*)(h + (size_t)ee[u].x * DIM))[q]
                              : make_uint2(0u, 0u);
        #pragma unroll
        for (int u = 0; u < 8; ++u)
            bf4_fma(vv[u], __int_as_float(ee[u].y), ax, ay, az, aw);
    }
}

// ---------------- gather layer 1: conv1(f32) = A_norm @ h + self + b1 ----------------
__global__ __launch_bounds__(256) void k_gather1(const int2* __restrict__ csr,
                                                 const int* __restrict__ rowptr,
                                                 const float* __restrict__ dinv,
                                                 const ushort* __restrict__ h,
                                                 const float* __restrict__ b1,
                                                 const int* __restrict__ root,
                                                 float* __restrict__ conv1,
                                                 float* __restrict__ out, int N) {
    int q = threadIdx.x & 31;
    int g = threadIdx.x >> 5;   // 0..7
    float4 bv = ((const float4*)b1)[q];
    int rt = root[0];
    for (int d = blockIdx.x * 8 + g; d < N; d += gridDim.x * 8) {
        int beg = rowptr[d], end = rowptr[d + 1];
        float ax = 0.f, ay = 0.f, az = 0.f, aw = 0.f;
        edge_accum(csr, beg, end, q, h, ax, ay, az, aw);
        float di = dinv[d], sl = di * di;
        uint2 hv = ((const uint2*)(h + (size_t)d * DIM))[q];
        float4 r;
        r.x = fmaf(__uint_as_float(hv.x << 16), sl, ax) + bv.x;
        r.y = fmaf(__uint_as_float(hv.x & 0xFFFF0000u), sl, ay) + bv.y;
        r.z = fmaf(__uint_as_float(hv.y << 16), sl, az) + bv.z;
        r.w = fmaf(__uint_as_float(hv.y & 0xFFFF0000u), sl, aw) + bv.w;
        ((float4*)(conv1 + (size_t)d * DIM))[q] = r;
        if (d == rt) ((float4*)out)[q] = r;   // conv1_root (no relu)
    }
}

// ---------------- gather layer 2 + relu + fused column-mean (grid-stride) ----------------
__global__ __launch_bounds__(256) void k_gather2(const int2* __restrict__ csr,
                                                 const int* __restrict__ rowptr,
                                                 const float* __restrict__ dinv,
                                                 const ushort* __restrict__ h,
                                                 const float* __restrict__ b2,
                                                 float* __restrict__ meanacc, int N) {
    int q = threadIdx.x & 31;
    int g = threadIdx.x >> 5;   // 0..7
    float4 bv = ((const float4*)b2)[q];
    float sx = 0.f, sy = 0.f, sz = 0.f, sw = 0.f;  // running column sum
    for (int d = blockIdx.x * 8 + g; d < N; d += gridDim.x * 8) {
        int beg = rowptr[d], end = rowptr[d + 1];
        float ax = 0.f, ay = 0.f, az = 0.f, aw = 0.f;
        edge_accum(csr, beg, end, q, h, ax, ay, az, aw);
        float di = dinv[d], sl = di * di;
        uint2 hv = ((const uint2*)(h + (size_t)d * DIM))[q];
        sx += fmaxf(fmaf(__uint_as_float(hv.x << 16), sl, ax) + bv.x, 0.f);
        sy += fmaxf(fmaf(__uint_as_float(hv.x & 0xFFFF0000u), sl, ay) + bv.y, 0.f);
        sz += fmaxf(fmaf(__uint_as_float(hv.y << 16), sl, az) + bv.z, 0.f);
        sw += fmaxf(fmaf(__uint_as_float(hv.y & 0xFFFF0000u), sl, aw) + bv.w, 0.f);
    }
    __shared__ float4 sp[256];
    sp[threadIdx.x] = make_float4(sx, sy, sz, sw);
    __syncthreads();
    if (threadIdx.x < 32) {
        float4 s = sp[threadIdx.x];
        #pragma unroll
        for (int gg = 1; gg < 8; ++gg) {
            float4 o = sp[gg * 32 + threadIdx.x];
            s.x += o.x; s.y += o.y; s.z += o.z; s.w += o.w;
        }
        unsafeAtomicAdd(&meanacc[q * 4 + 0], s.x);
        unsafeAtomicAdd(&meanacc[q * 4 + 1], s.y);
        unsafeAtomicAdd(&meanacc[q * 4 + 2], s.z);
        unsafeAtomicAdd(&meanacc[q * 4 + 3], s.w);
    }
}

__global__ __launch_bounds__(DIM) void k_reduce(const float* __restrict__ meanacc,
                                                float* __restrict__ out, int N) {
    int j = threadIdx.x;
    out[DIM + j] = meanacc[j] / (float)N;
}

extern "C" void kernel_launch(void* const* d_in, const int* in_sizes, int n_in,
                              void* d_out, int out_size, void* d_ws, size_t ws_size,
                              hipStream_t stream) {
    const float* posts = (const float*)d_in[0];
    const int*   eidx  = (const int*)d_in[1];
    const int*   root  = (const int*)d_in[2];
    const float* W1    = (const float*)d_in[3];
    const float* b1    = (const float*)d_in[4];
    const float* W2    = (const float*)d_in[5];
    const float* b2    = (const float*)d_in[6];
    float* out = (float*)d_out;

    int N = in_sizes[0] / DIM;
    int E = in_sizes[1] / 2;
    const int* src = eidx;
    const int* dst = eidx + E;
    int nseg = (N + 255) / 256;   // 196 for N=50000 (fits k_scanB's 256)

    char* ws = (char*)d_ws;
    size_t off = 0;
    auto alloc = [&](size_t bytes) {
        void* p = ws + off;
        off += (bytes + 511) & ~(size_t)511;
        return p;
    };
    int*    deg     = (int*)   alloc((size_t)N * 4);
    int*    rowptr  = (int*)   alloc((size_t)(N + 1) * 4);
    int*    cursor  = (int*)   alloc((size_t)N * 4);
    int*    segsum  = (int*)   alloc((size_t)nseg * 4);
    float*  dinv    = (float*) alloc((size_t)N * 4);
    float*  cvec    = (float*) alloc(DIM * 4);
    float*  meanacc = (float*) alloc(DIM * 4);
    int2*   csr     = (int2*)  alloc((size_t)E * 8);
    ushort* h       = (ushort*)alloc((size_t)N * DIM * 2);   // bf16 h1, then h2
    float*  conv1   = (float*) alloc((size_t)N * DIM * 4);   // conv1_out (f32)

    hipMemsetAsync(deg, 0, (size_t)N * 4, stream);
    hipMemsetAsync(meanacc, 0, DIM * 4, stream);

    // CSR build (once, shared by both layers); parallel 3-stage scan
    k_count<<<(E + 255) / 256, 256, 0, stream>>>(dst, deg, E);
    k_scanA<<<nseg, 256, 0, stream>>>(deg, rowptr, segsum, N);
    k_scanB<<<1, 256, 0, stream>>>(segsum, nseg);
    k_scanC<<<nseg, 256, 0, stream>>>(rowptr, segsum, cursor, N, E);
    k_dinv<<<(N + 255) / 256, 256, 0, stream>>>(deg, dinv, N);
    k_fill<<<(E + 255) / 256, 256, 0, stream>>>(src, dst, dinv, cursor, csr, E);

    // layer 1
    k_gemm<false, false><<<512, 256, 0, stream>>>(posts, W1, nullptr, h, N);
    k_gather1<<<2048, 256, 0, stream>>>(csr, rowptr, dinv, h, b1, root, conv1, out, N);

    // layer 2: h2 = cvec + relu(conv1) @ W2[128:], cvec = relu(post_root) @ W2[:128]
    k_cvec<<<1, DIM, 0, stream>>>(posts, root, W2, cvec);
    k_gemm<true, true><<<512, 256, 0, stream>>>(conv1, W2 + DIM * DIM, cvec, h, N);
    k_gather2<<<2048, 256, 0, stream>>>(csr, rowptr, dinv, h, b2, meanacc, N);
    k_reduce<<<1, DIM, 0, stream>>>(meanacc, out, N);
}

// Round 9
// 438.217 us; speedup vs baseline: 2.1633x; 1.0045x over previous
//
#include <hip/hip_runtime.h>

#define DIM 128
typedef unsigned int uint;
typedef unsigned short ushort;

// bf16 pack (RNE)
__device__ __forceinline__ ushort f2bf(float x) {
    uint u = __float_as_uint(x);
    u = u + 0x7FFFu + ((u >> 16) & 1u);
    return (ushort)(u >> 16);
}
__device__ __forceinline__ uint pack2(float a, float b) {
    return (uint)f2bf(a) | ((uint)f2bf(b) << 16);
}

// ---------------- degree count ----------------
__global__ __launch_bounds__(256) void k_count(const int* __restrict__ dst,
                                               int* __restrict__ deg, int E) {
    int t = blockIdx.x * 256 + threadIdx.x;
    if (t < E) atomicAdd(&deg[dst[t]], 1);
}

__global__ __launch_bounds__(256) void k_dinv(const int* __restrict__ deg,
                                              float* __restrict__ dinv, int N) {
    int t = blockIdx.x * 256 + threadIdx.x;
    if (t < N) dinv[t] = rsqrtf((float)(deg[t] + 1));  // +1 = self-loop
}

// ---------------- parallel exclusive scan: blockwise -> seg -> add ----------------
__global__ __launch_bounds__(256) void k_scanA(const int* __restrict__ deg,
                                               int* __restrict__ rowptr,
                                               int* __restrict__ segsum, int N) {
    int i = blockIdx.x * 256 + threadIdx.x;
    int v = (i < N) ? deg[i] : 0;
    __shared__ int ps[256];
    ps[threadIdx.x] = v;
    __syncthreads();
    for (int off = 1; off < 256; off <<= 1) {
        int u = (threadIdx.x >= off) ? ps[threadIdx.x - off] : 0;
        __syncthreads();
        ps[threadIdx.x] += u;
        __syncthreads();
    }
    if (i < N) rowptr[i] = ps[threadIdx.x] - v;   // exclusive within block
    if (threadIdx.x == 255) segsum[blockIdx.x] = ps[255];
}

__global__ __launch_bounds__(256) void k_scanB(int* __restrict__ segsum, int nseg) {
    int t = threadIdx.x;
    int v = (t < nseg) ? segsum[t] : 0;
    __shared__ int ps[256];
    ps[t] = v;
    __syncthreads();
    for (int off = 1; off < 256; off <<= 1) {
        int u = (t >= off) ? ps[t - off] : 0;
        __syncthreads();
        ps[t] += u;
        __syncthreads();
    }
    if (t < nseg) segsum[t] = ps[t] - v;
}

__global__ __launch_bounds__(256) void k_scanC(int* __restrict__ rowptr,
                                               const int* __restrict__ segsum,
                                               int* __restrict__ cursor, int N, int E) {
    int i = blockIdx.x * 256 + threadIdx.x;
    if (i < N) {
        int r = rowptr[i] + segsum[blockIdx.x];
        rowptr[i] = r;
        cursor[i] = r;
    }
    if (i == 0) rowptr[N] = E;
}

// ---------------- CSR fill: {src, weight} per edge, grouped by dst ----------------
__global__ __launch_bounds__(256) void k_fill(const int* __restrict__ src,
                                              const int* __restrict__ dst,
                                              const float* __restrict__ dinv,
                                              int* __restrict__ cursor,
                                              int2* __restrict__ csr, int E) {
    int e = blockIdx.x * 256 + threadIdx.x;
    if (e >= E) return;
    int s = src[e], d = dst[e];
    int p = atomicAdd(&cursor[d], 1);
    float w = dinv[s] * dinv[d];
    csr[p] = make_int2(s, __float_as_int(w));
}

// ---------------- dense GEMM: H(bf16) = (cvec +) f(X) @ W ----------------
template<bool RELU_IN, bool ADD_C>
__global__ __launch_bounds__(256) void k_gemm(const float* __restrict__ X,
                                              const float* __restrict__ W,
                                              const float* __restrict__ Cvec,
                                              ushort* __restrict__ H, int n) {
    __shared__ float sW[64 * DIM];   // 32 KB, one K-chunk of W [k2][j]
    __shared__ float sX[32][DIM];    // 16 KB
    const int jq = threadIdx.x & 31;
    const int rr = threadIdx.x >> 5;   // 0..7
    float4 cj = ADD_C ? ((const float4*)Cvec)[jq] : make_float4(0.f, 0.f, 0.f, 0.f);
    for (int base = blockIdx.x * 32; base < n; base += gridDim.x * 32) {
        __syncthreads();
        for (int u = threadIdx.x; u < 32 * 32; u += 256) {
            int row = u >> 5, c4 = u & 31;
            int gi = base + row;
            float4 v = make_float4(0.f, 0.f, 0.f, 0.f);
            if (gi < n) v = ((const float4*)(X + (size_t)gi * DIM))[c4];
            if (RELU_IN) {
                v.x = fmaxf(v.x, 0.f); v.y = fmaxf(v.y, 0.f);
                v.z = fmaxf(v.z, 0.f); v.w = fmaxf(v.w, 0.f);
            }
            ((float4*)sX[row])[c4] = v;
        }
        float4 a0 = cj, a1 = cj, a2 = cj, a3 = cj;
        for (int kk = 0; kk < DIM; kk += 64) {
            __syncthreads();
            for (int u = threadIdx.x; u < 64 * 32; u += 256)
                ((float4*)sW)[u] = ((const float4*)(W + (size_t)kk * DIM))[u];
            __syncthreads();
            #pragma unroll 8
            for (int k2 = 0; k2 < 64; ++k2) {
                int k = kk + k2;
                float4 w4 = ((const float4*)sW)[k2 * 32 + jq];
                float x0 = sX[rr * 4 + 0][k], x1 = sX[rr * 4 + 1][k];
                float x2 = sX[rr * 4 + 2][k], x3 = sX[rr * 4 + 3][k];
                a0.x = fmaf(x0, w4.x, a0.x); a0.y = fmaf(x0, w4.y, a0.y);
                a0.z = fmaf(x0, w4.z, a0.z); a0.w = fmaf(x0, w4.w, a0.w);
                a1.x = fmaf(x1, w4.x, a1.x); a1.y = fmaf(x1, w4.y, a1.y);
                a1.z = fmaf(x1, w4.z, a1.z); a1.w = fmaf(x1, w4.w, a1.w);
                a2.x = fmaf(x2, w4.x, a2.x); a2.y = fmaf(x2, w4.y, a2.y);
                a2.z = fmaf(x2, w4.z, a2.z); a2.w = fmaf(x2, w4.w, a2.w);
                a3.x = fmaf(x3, w4.x, a3.x); a3.y = fmaf(x3, w4.y, a3.y);
                a3.z = fmaf(x3, w4.z, a3.z); a3.w = fmaf(x3, w4.w, a3.w);
            }
        }
        int i0 = base + rr * 4;
        if (i0 + 0 < n) ((uint2*)(H + (size_t)(i0 + 0) * DIM))[jq] =
            make_uint2(pack2(a0.x, a0.y), pack2(a0.z, a0.w));
        if (i0 + 1 < n) ((uint2*)(H + (size_t)(i0 + 1) * DIM))[jq] =
            make_uint2(pack2(a1.x, a1.y), pack2(a1.z, a1.w));
        if (i0 + 2 < n) ((uint2*)(H + (size_t)(i0 + 2) * DIM))[jq] =
            make_uint2(pack2(a2.x, a2.y), pack2(a2.z, a2.w));
        if (i0 + 3 < n) ((uint2*)(H + (size_t)(i0 + 3) * DIM))[jq] =
            make_uint2(pack2(a3.x, a3.y), pack2(a3.z, a3.w));
    }
}

// ---------------- c[j] = sum_k relu(posts[root][k]) * W2[k][j] ----------------
__global__ __launch_bounds__(DIM) void k_cvec(const float* __restrict__ posts,
                                              const int* __restrict__ root,
                                              const float* __restrict__ W2,
                                              float* __restrict__ cvec) {
    int j = threadIdx.x;
    const float* xr = posts + (size_t)root[0] * DIM;
    float acc = 0.0f;
    #pragma unroll 8
    for (int k = 0; k < DIM; ++k)
        acc = fmaf(fmaxf(xr[k], 0.0f), W2[k * DIM + j], acc);
    cvec[j] = acc;
}

// unpack uint2 (4 bf16) and fma into acc
__device__ __forceinline__ void bf4_fma(uint2 p, float w,
                                        float& ax, float& ay, float& az, float& aw) {
    ax = fmaf(__uint_as_float(p.x << 16), w, ax);
    ay = fmaf(__uint_as_float(p.x & 0xFFFF0000u), w, ay);
    az = fmaf(__uint_as_float(p.y << 16), w, az);
    aw = fmaf(__uint_as_float(p.y & 0xFFFF0000u), w, aw);
}

// 8-edge-deep accumulate of bf16 h rows into (ax..aw) for lane-quad q.
// NOTE: requires the caller kernel to grant enough VGPRs (launch_bounds min-waves=4
// -> 128 VGPR cap) so all 8 csr loads and 8 row loads stay in flight.
__device__ __forceinline__ void edge_accum(const int2* __restrict__ csr,
                                           int beg, int end, int q,
                                           const ushort* __restrict__ h,
                                           float& ax, float& ay, float& az, float& aw) {
    int e = beg;
    for (; e + 8 <= end; e += 8) {
        int2 ee[8];
        uint2 vv[8];
        #pragma unroll
        for (int u = 0; u < 8; ++u) ee[u] = csr[e + u];
        #pragma unroll
        for (int u = 0; u < 8; ++u)
            vv[u] = ((const uint2*)(h + (size_t)ee[u].x * DIM))[q];
        #pragma unroll
        for (int u = 0; u < 8; ++u)
            bf4_fma(vv[u], __int_as_float(ee[u].y), ax, ay, az, aw);
    }
    int rem = end - e;
    if (rem > 0) {
        int2 ee[8];
        uint2 vv[8];
        #pragma unroll
        for (int u = 0; u < 8; ++u)
            ee[u] = (u < rem) ? csr[e + u] : make_int2(0, 0);
        #pragma unroll
        for (int u = 0; u < 8; ++u)
            vv[u] = (u < rem) ? ((const uint2*)(h + (size_t)ee[u].x * DIM))[q]
                              : make_uint2(0u, 0u);
        #pragma unroll
        for (int u = 0; u < 8; ++u)
            bf4_fma(vv[u], __int_as_float(ee[u].y), ax, ay, az, aw);
    }
}

// ---------------- gather layer 1: conv1(f32) = A_norm @ h + self + b1 ----------------
__global__ __launch_bounds__(256, 4) void k_gather1(const int2* __restrict__ csr,
                                                    const int* __restrict__ rowptr,
                                                    const float* __restrict__ dinv,
                                                    const ushort* __restrict__ h,
                                                    const float* __restrict__ b1,
                                                    const int* __restrict__ root,
                                                    float* __restrict__ conv1,
                                                    float* __restrict__ out, int N) {
    int q = threadIdx.x & 31;
    int g = threadIdx.x >> 5;   // 0..7
    float4 bv = ((const float4*)b1)[q];
    int rt = root[0];
    for (int d = blockIdx.x * 8 + g; d < N; d += gridDim.x * 8) {
        int beg = rowptr[d], end = rowptr[d + 1];
        float ax = 0.f, ay = 0.f, az = 0.f, aw = 0.f;
        edge_accum(csr, beg, end, q, h, ax, ay, az, aw);
        float di = dinv[d], sl = di * di;
        uint2 hv = ((const uint2*)(h + (size_t)d * DIM))[q];
        float4 r;
        r.x = fmaf(__uint_as_float(hv.x << 16), sl, ax) + bv.x;
        r.y = fmaf(__uint_as_float(hv.x & 0xFFFF0000u), sl, ay) + bv.y;
        r.z = fmaf(__uint_as_float(hv.y << 16), sl, az) + bv.z;
        r.w = fmaf(__uint_as_float(hv.y & 0xFFFF0000u), sl, aw) + bv.w;
        ((float4*)(conv1 + (size_t)d * DIM))[q] = r;
        if (d == rt) ((float4*)out)[q] = r;   // conv1_root (no relu)
    }
}

// ---------------- gather layer 2 + relu + fused column-mean (grid-stride) ----------------
__global__ __launch_bounds__(256, 4) void k_gather2(const int2* __restrict__ csr,
                                                    const int* __restrict__ rowptr,
                                                    const float* __restrict__ dinv,
                                                    const ushort* __restrict__ h,
                                                    const float* __restrict__ b2,
                                                    float* __restrict__ meanacc, int N) {
    int q = threadIdx.x & 31;
    int g = threadIdx.x >> 5;   // 0..7
    float4 bv = ((const float4*)b2)[q];
    float sx = 0.f, sy = 0.f, sz = 0.f, sw = 0.f;  // running column sum
    for (int d = blockIdx.x * 8 + g; d < N; d += gridDim.x * 8) {
        int beg = rowptr[d], end = rowptr[d + 1];
        float ax = 0.f, ay = 0.f, az = 0.f, aw = 0.f;
        edge_accum(csr, beg, end, q, h, ax, ay, az, aw);
        float di = dinv[d], sl = di * di;
        uint2 hv = ((const uint2*)(h + (size_t)d * DIM))[q];
        sx += fmaxf(fmaf(__uint_as_float(hv.x << 16), sl, ax) + bv.x, 0.f);
        sy += fmaxf(fmaf(__uint_as_float(hv.x & 0xFFFF0000u), sl, ay) + bv.y, 0.f);
        sz += fmaxf(fmaf(__uint_as_float(hv.y << 16), sl, az) + bv.z, 0.f);
        sw += fmaxf(fmaf(__uint_as_float(hv.y & 0xFFFF0000u), sl, aw) + bv.w, 0.f);
    }
    __shared__ float4 sp[256];
    sp[threadIdx.x] = make_float4(sx, sy, sz, sw);
    __syncthreads();
    if (threadIdx.x < 32) {
        float4 s = sp[threadIdx.x];
        #pragma unroll
        for (int gg = 1; gg < 8; ++gg) {
            float4 o = sp[gg * 32 + threadIdx.x];
            s.x += o.x; s.y += o.y; s.z += o.z; s.w += o.w;
        }
        unsafeAtomicAdd(&meanacc[q * 4 + 0], s.x);
        unsafeAtomicAdd(&meanacc[q * 4 + 1], s.y);
        unsafeAtomicAdd(&meanacc[q * 4 + 2], s.z);
        unsafeAtomicAdd(&meanacc[q * 4 + 3], s.w);
    }
}

__global__ __launch_bounds__(DIM) void k_reduce(const float* __restrict__ meanacc,
                                                float* __restrict__ out, int N) {
    int j = threadIdx.x;
    out[DIM + j] = meanacc[j] / (float)N;
}

extern "C" void kernel_launch(void* const* d_in, const int* in_sizes, int n_in,
                              void* d_out, int out_size, void* d_ws, size_t ws_size,
                              hipStream_t stream) {
    const float* posts = (const float*)d_in[0];
    const int*   eidx  = (const int*)d_in[1];
    const int*   root  = (const int*)d_in[2];
    const float* W1    = (const float*)d_in[3];
    const float* b1    = (const float*)d_in[4];
    const float* W2    = (const float*)d_in[5];
    const float* b2    = (const float*)d_in[6];
    float* out = (float*)d_out;

    int N = in_sizes[0] / DIM;
    int E = in_sizes[1] / 2;
    const int* src = eidx;
    const int* dst = eidx + E;
    int nseg = (N + 255) / 256;   // 196 for N=50000 (fits k_scanB's 256)

    char* ws = (char*)d_ws;
    size_t off = 0;
    auto alloc = [&](size_t bytes) {
        void* p = ws + off;
        off += (bytes + 511) & ~(size_t)511;
        return p;
    };
    int*    deg     = (int*)   alloc((size_t)N * 4);
    int*    rowptr  = (int*)   alloc((size_t)(N + 1) * 4);
    int*    cursor  = (int*)   alloc((size_t)N * 4);
    int*    segsum  = (int*)   alloc((size_t)nseg * 4);
    float*  dinv    = (float*) alloc((size_t)N * 4);
    float*  cvec    = (float*) alloc(DIM * 4);
    float*  meanacc = (float*) alloc(DIM * 4);
    int2*   csr     = (int2*)  alloc((size_t)E * 8);
    ushort* h       = (ushort*)alloc((size_t)N * DIM * 2);   // bf16 h1, then h2
    float*  conv1   = (float*) alloc((size_t)N * DIM * 4);   // conv1_out (f32)

    hipMemsetAsync(deg, 0, (size_t)N * 4, stream);
    hipMemsetAsync(meanacc, 0, DIM * 4, stream);

    // CSR build (once, shared by both layers); parallel 3-stage scan
    k_count<<<(E + 255) / 256, 256, 0, stream>>>(dst, deg, E);
    k_scanA<<<nseg, 256, 0, stream>>>(deg, rowptr, segsum, N);
    k_scanB<<<1, 256, 0, stream>>>(segsum, nseg);
    k_scanC<<<nseg, 256, 0, stream>>>(rowptr, segsum, cursor, N, E);
    k_dinv<<<(N + 255) / 256, 256, 0, stream>>>(deg, dinv, N);
    k_fill<<<(E + 255) / 256, 256, 0, stream>>>(src, dst, dinv, cursor, csr, E);

    // layer 1
    k_gemm<false, false><<<512, 256, 0, stream>>>(posts, W1, nullptr, h, N);
    k_gather1<<<2048, 256, 0, stream>>>(csr, rowptr, dinv, h, b1, root, conv1, out, N);

    // layer 2: h2 = cvec + relu(conv1) @ W2[128:], cvec = relu(post_root) @ W2[:128]
    k_cvec<<<1, DIM, 0, stream>>>(posts, root, W2, cvec);
    k_gemm<true, true><<<512, 256, 0, stream>>>(conv1, W2 + DIM * DIM, cvec, h, N);
    k_gather2<<<2048, 256, 0, stream>>>(csr, rowptr, dinv, h, b2, meanacc, N);
    k_reduce<<<1, DIM, 0, stream>>>(meanacc, out, N);
}